// Round 11
// baseline (283.715 us; speedup 1.0000x reference)
//
#include <hip/hip_runtime.h>
#include <hip/hip_bf16.h>

// GCNBlock: 6-dispatch pipeline (R11 = best-of-all-rounds consolidation).
//   1 init_prep:  zero deg_cnt ; repack W -> Wb bf16
//   2 count_gemm: count edges -> packed(rank,dst) || single-phase 64-row GEMM
//                 (R10's 2-phase LDS halving reverted: occupancy was NOT
//                 LDS-capped -- 30% at both sizes; atomic pass is bound by
//                 device-scope atomic throughput, and 2-phase cost +10us)
//   3 build_csr:  ONE kernel: per-block base via strided L2 sum of lower
//                 deg_cnt + local scan + dinv  (replaces block_sums/scan/write)
//   4 fill:       contention-free scatter via packed(rank,dst)
//   5 aggregate:  R9-proven 2 rows/wave, 32 lanes x ushort8 (16B) gather
//   6 norm_prelu: redundant partials reduce + LN + PReLU
// Ledger: R4 1-addr f64 atomics=CAS livelock; R5 atomic-bump fill=contention;
// R6 mega-fusion=VGPR spill; R7 arbitrary bucket order=locality loss; R8
// fused scatter=dependent chain; R10 2-phase gemm=slower, occupancy unmoved.
// N=50000, E=800000, F=256

#define F 256
#define EPSV 1e-5f

typedef __attribute__((ext_vector_type(8))) short short8;
typedef __attribute__((ext_vector_type(8))) unsigned short ushort8v;
typedef __attribute__((ext_vector_type(4))) float f32x4;

__device__ __forceinline__ unsigned short f2bf(float f) {
  union { float f; unsigned u; } v; v.f = f;
  unsigned r = v.u + 0x7fffu + ((v.u >> 16) & 1u);  // RNE
  return (unsigned short)(r >> 16);
}

__device__ __forceinline__ float bf2f(unsigned short u) {
  union { unsigned u; float f; } v; v.u = ((unsigned)u) << 16; return v.f;
}

// ---- 1: zero deg_cnt (blocks < NB) ; prep Wb (blocks >= NB) ----------------

__global__ void init_prep(int* __restrict__ deg_cnt, int N, int NB,
                          const float* __restrict__ W, unsigned short* __restrict__ Wb) {
  if ((int)blockIdx.x < NB) {
    int i = blockIdx.x * 256 + threadIdx.x;
    if (i < N) deg_cnt[i] = 0;
    return;
  }
  int gid = (blockIdx.x - NB) * 256 + threadIdx.x;  // 65536 total
  int j = gid & 7;
  int lane = (gid >> 3) & 63;
  int kc = (gid >> 9) & 7;
  int tt = gid >> 12;
  int k = kc * 32 + (lane >> 4) * 8 + j;
  int n = tt * 16 + (lane & 15);
  Wb[gid] = f2bf(W[k * 256 + n]);
}

// ---- 2: count+pack (blocks < eb) ; gemm 64-row tiles (blocks >= eb) --------
// packed[e] = (rank << 17) | dst  (dst < 2^17; rank < 2^15, Poisson(16)).
// GEMM writes h bf16 UNSCALED (dinv applied at gather time in aggregate).

__global__ void count_gemm(const int* __restrict__ dst, int* __restrict__ deg_cnt,
                           int* __restrict__ packed, int E, int eb,
                           const float* __restrict__ x, const unsigned short* __restrict__ Wb,
                           ushort4* __restrict__ hb, int N) {
  // +8 pad: row stride 528B -> conflict-free ds_read_b128 fragments.
  __shared__ unsigned short A[64][264];  // 33792 B

  if ((int)blockIdx.x < eb) {
    int e = blockIdx.x * 256 + threadIdx.x;
    if (e < E) {
      int d = dst[e];
      int pos = atomicAdd(&deg_cnt[d], 1);
      packed[e] = (pos << 17) | d;
    }
    return;
  }

  int m0 = (blockIdx.x - eb) * 64;
  int t = threadIdx.x;
  int lane = t & 63;
  int wave = t >> 6;
  int q = lane >> 4;

  // stage A: 64 rows x 256 cols fp32->bf16, coalesced
#pragma unroll
  for (int j = 0; j < 16; ++j) {
    int idx = j * 256 + t;
    int row = idx >> 6;
    int c4 = idx & 63;
    int gr = m0 + row;
    int grc = gr < N ? gr : N - 1;
    f32x4 v = __builtin_nontemporal_load((const f32x4*)(x + (size_t)grc * F + c4 * 4));
    ushort4 u;
    u.x = f2bf(v[0]); u.y = f2bf(v[1]); u.z = f2bf(v[2]); u.w = f2bf(v[3]);
    *(ushort4*)&A[row][c4 * 4] = u;
  }
  __syncthreads();

  f32x4 acc[4][4];
#pragma unroll
  for (int m = 0; m < 4; ++m)
#pragma unroll
    for (int tt = 0; tt < 4; ++tt)
      acc[m][tt] = (f32x4){0.f, 0.f, 0.f, 0.f};

  int arow = lane & 15;
  for (int kc = 0; kc < 8; ++kc) {
    short8 a[4];
#pragma unroll
    for (int m = 0; m < 4; ++m)
      a[m] = *(const short8*)&A[m * 16 + arow][kc * 32 + q * 8];
#pragma unroll
    for (int tt = 0; tt < 4; ++tt) {
      const short8 b = *(const short8*)(Wb + (((wave * 4 + tt) * 8 + kc) * 64 + lane) * 8);
#pragma unroll
      for (int m = 0; m < 4; ++m)
        acc[m][tt] = __builtin_amdgcn_mfma_f32_16x16x32_bf16(a[m], b, acc[m][tt], 0, 0, 0);
    }
  }
  __syncthreads();

  // epilogue: bf16 repack via LDS, coalesced store (h UNSCALED)
  int ccol = lane & 15;
#pragma unroll
  for (int m = 0; m < 4; ++m) {
#pragma unroll
    for (int rr = 0; rr < 4; ++rr) {
      int lrow = m * 16 + q * 4 + rr;
#pragma unroll
      for (int tt = 0; tt < 4; ++tt)
        A[lrow][(wave * 4 + tt) * 16 + ccol] = f2bf(acc[m][tt][rr]);
    }
  }
  __syncthreads();
#pragma unroll
  for (int j = 0; j < 16; ++j) {
    int idx = j * 256 + t;
    int row = idx >> 6;
    int c4 = idx & 63;
    int grow = m0 + row;
    if (grow < N) hb[(size_t)grow * 64 + c4] = *(const ushort4*)&A[row][c4 * 4];
  }
}

// ---- 3: build_csr: ONE kernel (base via strided L2 sum + local scan) -------
// Block b: base = sum(deg_cnt[0..b*256)) computed by strided reduction (L2-hot,
// ~20MB total across grid); then block-local inclusive scan. Monotone CSR.

__global__ void build_csr(const int* __restrict__ deg_cnt, float* __restrict__ dinv,
                          int* __restrict__ csr_ptr, int N, int E) {
  __shared__ int s[256];
  __shared__ int sbase;
  int t = threadIdx.x;
  int start = blockIdx.x * 256;

  int part = 0;
  for (int i = t; i < start; i += 256) part += deg_cnt[i];
  s[t] = part;
  __syncthreads();
  for (int off = 128; off > 0; off >>= 1) {
    if (t < off) s[t] += s[t + off];
    __syncthreads();
  }
  if (t == 0) sbase = s[0];
  __syncthreads();
  int base = sbase;
  __syncthreads();  // everyone has base; safe to reuse s

  int i = start + t;
  int d = (i < N) ? deg_cnt[i] : 0;
  if (i < N) dinv[i] = rsqrtf((float)(d + 1));  // +1 self loop
  s[t] = d;
  __syncthreads();
  for (int off = 1; off < 256; off <<= 1) {
    int xx = (t >= off) ? s[t - off] : 0;
    __syncthreads();
    s[t] += xx;
    __syncthreads();
  }
  if (i < N) csr_ptr[i] = base + s[t] - d;  // exclusive (bucket START)
  if (i == 0) csr_ptr[N] = E;
}

// ---- 4: fill via packed(rank,dst) (contention-free scatter) ----------------

__global__ void fill(const int* __restrict__ src, const int* __restrict__ packed,
                     const int* __restrict__ csr_ptr, int* __restrict__ csr_src, int E) {
  int e = blockIdx.x * 256 + threadIdx.x;
  if (e < E) {
    int pk = packed[e];
    int d = pk & 0x1FFFF;
    int r = pk >> 17;
    csr_src[csr_ptr[d] + r] = src[e];
  }
}

// ---- 5: aggregate -- 2 rows per wave, 32 lanes x 16B (ushort8) per row -----
// hb UNSCALED; weight w[j] = dinv[src_j] (0 for pad).  R9-proven.

__global__ void aggregate(const ushort4* __restrict__ hb, const int* __restrict__ csr_ptr,
                          const int* __restrict__ csr_src, const float* __restrict__ dinv,
                          const float* __restrict__ conv_bias, float* __restrict__ out,
                          double2* __restrict__ partials, int N) {
  int wave = threadIdx.x >> 6;
  int lane = threadIdx.x & 63;
  int half = lane >> 5;
  int l = lane & 31;
  int row = blockIdx.x * 8 + wave * 2 + half;
  float s1 = 0.f, s2 = 0.f;
  const unsigned short* hbs = (const unsigned short*)hb;

  if (row < N) {
    float di = dinv[row];
    int b0 = csr_ptr[row], b1 = csr_ptr[row + 1];
    ushort8v sv = *(const ushort8v*)(hbs + (size_t)row * 256 + l * 8);
    float acc[8];
#pragma unroll
    for (int c = 0; c < 8; ++c) acc[c] = bf2f(sv[c]) * di;

    for (int e = b0; e < b1; e += 8) {
      int idx[8];
#pragma unroll
      for (int j = 0; j < 8; ++j) {
        int ee = e + j;
        idx[j] = csr_src[ee < b1 ? ee : b1 - 1];
      }
      ushort8v v[8];
#pragma unroll
      for (int j = 0; j < 8; ++j)
        v[j] = *(const ushort8v*)(hbs + (size_t)idx[j] * 256 + l * 8);
      float w[8];
#pragma unroll
      for (int j = 0; j < 8; ++j) w[j] = dinv[idx[j]];
#pragma unroll
      for (int j = 0; j < 8; ++j) {
        float m = (e + j < b1) ? w[j] : 0.f;
#pragma unroll
        for (int c = 0; c < 8; ++c)
          acc[c] = fmaf(bf2f(v[j][c]), m, acc[c]);
      }
    }

    const f32x4 ba = *(const f32x4*)(conv_bias + l * 8);
    const f32x4 bb = *(const f32x4*)(conv_bias + l * 8 + 4);
    f32x4 o0, o1;
#pragma unroll
    for (int c = 0; c < 4; ++c) {
      o0[c] = fmaf(acc[c], di, ba[c]);
      o1[c] = fmaf(acc[c + 4], di, bb[c]);
    }
    float* orow = out + (size_t)row * 256 + l * 8;
    __builtin_nontemporal_store(o0, (f32x4*)orow);
    __builtin_nontemporal_store(o1, (f32x4*)(orow + 4));
#pragma unroll
    for (int c = 0; c < 4; ++c) {
      s1 += o0[c] + o1[c];
      s2 += o0[c] * o0[c] + o1[c] * o1[c];
    }
  }

  __shared__ float r1[256];
  __shared__ float r2[256];
  int t = threadIdx.x;
  r1[t] = s1;
  r2[t] = s2;
  __syncthreads();
  for (int off = 128; off > 0; off >>= 1) {
    if (t < off) { r1[t] += r1[t + off]; r2[t] += r2[t + off]; }
    __syncthreads();
  }
  if (t == 0) {
    double2 pp;
    pp.x = (double)r1[0];
    pp.y = (double)r2[0];
    partials[blockIdx.x] = pp;
  }
}

// ---- 6: redundant partials reduce + LayerNorm(graph) + PReLU ---------------

__global__ void norm_prelu(float* __restrict__ out, const double2* __restrict__ partials,
                           int nb, const float* __restrict__ lw, const float* __restrict__ lb,
                           const float* __restrict__ pa, int n4, double cnt) {
  __shared__ double q1[1024];
  __shared__ double q2[1024];
  __shared__ float sstats[2];
  int t = threadIdx.x;
  double a1 = 0.0, a2 = 0.0;
  for (int i = t; i < nb; i += 1024) {
    double2 pp = partials[i];
    a1 += pp.x;
    a2 += pp.y;
  }
  q1[t] = a1;
  q2[t] = a2;
  __syncthreads();
  for (int off = 512; off > 0; off >>= 1) {
    if (t < off) { q1[t] += q1[t + off]; q2[t] += q2[t + off]; }
    __syncthreads();
  }
  if (t == 0) {
    double mu = q1[0] / cnt;
    double var = q2[0] / cnt - mu * mu;
    if (var < 0) var = 0;
    sstats[0] = (float)mu;
    sstats[1] = (float)(1.0 / (sqrt(var) + (double)EPSV));
  }
  __syncthreads();
  float mu = sstats[0];
  float inv = sstats[1];
  float a = pa[0];
  int stride = gridDim.x * 1024;
  for (int i = blockIdx.x * 1024 + t; i < n4; i += stride) {
    int c4 = (i & 63) * 4;
    const f32x4 w = *(const f32x4*)(lw + c4);
    const f32x4 b = *(const f32x4*)(lb + c4);
    f32x4 v = __builtin_nontemporal_load((const f32x4*)(out + (size_t)i * 4));
    f32x4 y;
#pragma unroll
    for (int j = 0; j < 4; ++j) {
      float yv = (v[j] - mu) * inv * w[j] + b[j];
      y[j] = yv >= 0.f ? yv : a * yv;
    }
    __builtin_nontemporal_store(y, (f32x4*)(out + (size_t)i * 4));
  }
}

// ---- launch ---------------------------------------------------------------

extern "C" void kernel_launch(void* const* d_in, const int* in_sizes, int n_in,
                              void* d_out, int out_size, void* d_ws, size_t ws_size,
                              hipStream_t stream) {
  const float* x = (const float*)d_in[0];
  const int* eidx = (const int*)d_in[1];
  const float* W = (const float*)d_in[3];
  const float* conv_bias = (const float*)d_in[4];
  const float* ln_w = (const float*)d_in[5];
  const float* ln_b = (const float*)d_in[6];
  const float* prelu_a = (const float*)d_in[7];
  float* out = (float*)d_out;

  int N = in_sizes[0] / F;
  int E = in_sizes[1] / 2;
  const int* src = eidx;
  const int* dst = eidx + E;

  int nAggBlocks = (N + 7) / 8;
  int eb = (E + 255) / 256;
  int gemmb = (N + 63) / 64;
  int NB = (N + 255) / 256;

  char* p = (char*)d_ws;
  auto carve = [&](size_t bytes) { char* r = p; p += (bytes + 255) & ~(size_t)255; return r; };
  ushort4* hb    = (ushort4*)carve((size_t)N * 64 * sizeof(ushort4));  // bf16 h (unscaled)
  unsigned short* Wb = (unsigned short*)carve((size_t)F * F * sizeof(short));
  int* deg_cnt   = (int*)carve((size_t)N * sizeof(int));
  int* packed    = (int*)carve((size_t)E * sizeof(int));
  float* dinv    = (float*)carve((size_t)N * sizeof(float));
  int* csr_ptr   = (int*)carve((size_t)(N + 1) * sizeof(int));
  int* csr_src   = (int*)carve((size_t)E * sizeof(int));
  double2* partials = (double2*)carve((size_t)nAggBlocks * sizeof(double2));

  init_prep<<<NB + 256, 256, 0, stream>>>(deg_cnt, N, NB, W, Wb);
  count_gemm<<<eb + gemmb, 256, 0, stream>>>(dst, deg_cnt, packed, E, eb, x, Wb, hb, N);
  build_csr<<<NB, 256, 0, stream>>>(deg_cnt, dinv, csr_ptr, N, E);
  fill<<<eb, 256, 0, stream>>>(src, packed, csr_ptr, csr_src, E);
  aggregate<<<nAggBlocks, 256, 0, stream>>>(hb, csr_ptr, csr_src, dinv,
                                            conv_bias, out, partials, N);
  int n4 = N * (F / 4);
  norm_prelu<<<256, 1024, 0, stream>>>(out, partials, nAggBlocks, ln_w, ln_b, prelu_a,
                                       n4, (double)N * (double)F);
}

// Round 12
// 262.480 us; speedup vs baseline: 1.0809x; 1.0809x over previous
//
#include <hip/hip_runtime.h>
#include <hip/hip_bf16.h>

// GCNBlock: 7-dispatch pipeline (R12 = measured-best components only).
//   1 init_prep:  zero deg_cnt ; repack W -> Wb bf16
//   2 count_gemm: count edges -> packed(rank<<17|dst) || single-phase 64-row
//                 GEMM (R11-measured 63us co-dispatch)
//   3 block_sums: per-block degree sums + dinv (R9/R10-measured ~3us)
//   4 write_csr:  folded bsum scan (NB<=256) + local scan (R10-measured)
//                 [R11's build_csr REVERTED: O(NB^2) strided base sum cost
//                  ~15-20us -- worse than the two tiny kernels it replaced]
//   5 fill:       contention-free scatter via packed (R10-measured)
//   6 aggregate:  2 rows/wave, 32 lanes x ushort8 (R9-proven; R11: 62.5us,
//                 3.9TB/s, 49% HBM -- near gather BW ceiling)
//   7 norm_prelu: redundant partials reduce + LN + PReLU (R9-proven)
// Ledger: R4 1-addr f64 atomics=CAS livelock; R5 atomic-bump fill=contention;
// R6 mega-fusion=VGPR spill; R7 arbitrary bucket order=locality loss; R8
// fused scatter=dependent chain; R10 2-phase gemm=slower; R11 quadratic fuse.
// N=50000, E=800000, F=256

#define F 256
#define EPSV 1e-5f

typedef __attribute__((ext_vector_type(8))) short short8;
typedef __attribute__((ext_vector_type(8))) unsigned short ushort8v;
typedef __attribute__((ext_vector_type(4))) float f32x4;

__device__ __forceinline__ unsigned short f2bf(float f) {
  union { float f; unsigned u; } v; v.f = f;
  unsigned r = v.u + 0x7fffu + ((v.u >> 16) & 1u);  // RNE
  return (unsigned short)(r >> 16);
}

__device__ __forceinline__ float bf2f(unsigned short u) {
  union { unsigned u; float f; } v; v.u = ((unsigned)u) << 16; return v.f;
}

// ---- 1: zero deg_cnt (blocks < NB) ; prep Wb (blocks >= NB) ----------------

__global__ void init_prep(int* __restrict__ deg_cnt, int N, int NB,
                          const float* __restrict__ W, unsigned short* __restrict__ Wb) {
  if ((int)blockIdx.x < NB) {
    int i = blockIdx.x * 256 + threadIdx.x;
    if (i < N) deg_cnt[i] = 0;
    return;
  }
  int gid = (blockIdx.x - NB) * 256 + threadIdx.x;  // 65536 total
  int j = gid & 7;
  int lane = (gid >> 3) & 63;
  int kc = (gid >> 9) & 7;
  int tt = gid >> 12;
  int k = kc * 32 + (lane >> 4) * 8 + j;
  int n = tt * 16 + (lane & 15);
  Wb[gid] = f2bf(W[k * 256 + n]);
}

// ---- 2: count+pack (blocks < eb) ; gemm 64-row tiles (blocks >= eb) --------
// packed[e] = (rank << 17) | dst  (dst < 2^17; rank < 2^15, Poisson(16)).
// GEMM writes h bf16 UNSCALED (dinv applied at gather time in aggregate).

__global__ void count_gemm(const int* __restrict__ dst, int* __restrict__ deg_cnt,
                           int* __restrict__ packed, int E, int eb,
                           const float* __restrict__ x, const unsigned short* __restrict__ Wb,
                           ushort4* __restrict__ hb, int N) {
  // +8 pad: row stride 528B -> conflict-free ds_read_b128 fragments.
  __shared__ unsigned short A[64][264];  // 33792 B

  if ((int)blockIdx.x < eb) {
    int e = blockIdx.x * 256 + threadIdx.x;
    if (e < E) {
      int d = dst[e];
      int pos = atomicAdd(&deg_cnt[d], 1);
      packed[e] = (pos << 17) | d;
    }
    return;
  }

  int m0 = (blockIdx.x - eb) * 64;
  int t = threadIdx.x;
  int lane = t & 63;
  int wave = t >> 6;
  int q = lane >> 4;

  // stage A: 64 rows x 256 cols fp32->bf16, coalesced
#pragma unroll
  for (int j = 0; j < 16; ++j) {
    int idx = j * 256 + t;
    int row = idx >> 6;
    int c4 = idx & 63;
    int gr = m0 + row;
    int grc = gr < N ? gr : N - 1;
    f32x4 v = __builtin_nontemporal_load((const f32x4*)(x + (size_t)grc * F + c4 * 4));
    ushort4 u;
    u.x = f2bf(v[0]); u.y = f2bf(v[1]); u.z = f2bf(v[2]); u.w = f2bf(v[3]);
    *(ushort4*)&A[row][c4 * 4] = u;
  }
  __syncthreads();

  f32x4 acc[4][4];
#pragma unroll
  for (int m = 0; m < 4; ++m)
#pragma unroll
    for (int tt = 0; tt < 4; ++tt)
      acc[m][tt] = (f32x4){0.f, 0.f, 0.f, 0.f};

  int arow = lane & 15;
  for (int kc = 0; kc < 8; ++kc) {
    short8 a[4];
#pragma unroll
    for (int m = 0; m < 4; ++m)
      a[m] = *(const short8*)&A[m * 16 + arow][kc * 32 + q * 8];
#pragma unroll
    for (int tt = 0; tt < 4; ++tt) {
      const short8 b = *(const short8*)(Wb + (((wave * 4 + tt) * 8 + kc) * 64 + lane) * 8);
#pragma unroll
      for (int m = 0; m < 4; ++m)
        acc[m][tt] = __builtin_amdgcn_mfma_f32_16x16x32_bf16(a[m], b, acc[m][tt], 0, 0, 0);
    }
  }
  __syncthreads();

  // epilogue: bf16 repack via LDS, coalesced store (h UNSCALED)
  int ccol = lane & 15;
#pragma unroll
  for (int m = 0; m < 4; ++m) {
#pragma unroll
    for (int rr = 0; rr < 4; ++rr) {
      int lrow = m * 16 + q * 4 + rr;
#pragma unroll
      for (int tt = 0; tt < 4; ++tt)
        A[lrow][(wave * 4 + tt) * 16 + ccol] = f2bf(acc[m][tt][rr]);
    }
  }
  __syncthreads();
#pragma unroll
  for (int j = 0; j < 16; ++j) {
    int idx = j * 256 + t;
    int row = idx >> 6;
    int c4 = idx & 63;
    int grow = m0 + row;
    if (grow < N) hb[(size_t)grow * 64 + c4] = *(const ushort4*)&A[row][c4 * 4];
  }
}

// ---- 3: per-block degree sums + dinv ---------------------------------------

__global__ void block_sums(const int* __restrict__ deg_cnt, int* __restrict__ bsum,
                           float* __restrict__ dinv, int N) {
  __shared__ int s[256];
  int t = threadIdx.x;
  int i = blockIdx.x * 256 + t;
  int d = (i < N) ? deg_cnt[i] : 0;
  if (i < N) dinv[i] = rsqrtf((float)(d + 1));  // +1 self loop
  s[t] = d;
  __syncthreads();
  for (int off = 128; off > 0; off >>= 1) {
    if (t < off) s[t] += s[t + off];
    __syncthreads();
  }
  if (t == 0) bsum[blockIdx.x] = s[0];
}

// ---- 4: write_csr with folded bsum scan (NB <= 256) ------------------------
// Each block redundantly scans all bsums in LDS (monotone CSR preserved).

__global__ void write_csr(const int* __restrict__ deg_cnt, const int* __restrict__ bsum,
                          int* __restrict__ csr_ptr, int N, int E, int NB) {
  __shared__ int sb[256];
  __shared__ int s[256];
  int t = threadIdx.x;
  int bv = (t < NB) ? bsum[t] : 0;
  sb[t] = bv;
  __syncthreads();
  for (int off = 1; off < 256; off <<= 1) {
    int xx = (t >= off) ? sb[t - off] : 0;
    __syncthreads();
    sb[t] += xx;
    __syncthreads();
  }
  int boff = (blockIdx.x > 0) ? sb[blockIdx.x - 1] : 0;
  int i = blockIdx.x * 256 + t;
  int v = (i < N) ? deg_cnt[i] : 0;
  s[t] = v;
  __syncthreads();
  for (int off = 1; off < 256; off <<= 1) {
    int xx = (t >= off) ? s[t - off] : 0;
    __syncthreads();
    s[t] += xx;
    __syncthreads();
  }
  if (i < N) csr_ptr[i] = boff + s[t] - v;
  if (i == 0) csr_ptr[N] = E;
}

// ---- 5: fill via packed(rank,dst) (contention-free scatter) ----------------

__global__ void fill(const int* __restrict__ src, const int* __restrict__ packed,
                     const int* __restrict__ csr_ptr, int* __restrict__ csr_src, int E) {
  int e = blockIdx.x * 256 + threadIdx.x;
  if (e < E) {
    int pk = packed[e];
    int d = pk & 0x1FFFF;
    int r = pk >> 17;
    csr_src[csr_ptr[d] + r] = src[e];
  }
}

// ---- 6: aggregate -- 2 rows per wave, 32 lanes x 16B (ushort8) per row -----
// hb UNSCALED; weight w[j] = dinv[src_j] (0 for pad).  R9-proven.

__global__ void aggregate(const ushort4* __restrict__ hb, const int* __restrict__ csr_ptr,
                          const int* __restrict__ csr_src, const float* __restrict__ dinv,
                          const float* __restrict__ conv_bias, float* __restrict__ out,
                          double2* __restrict__ partials, int N) {
  int wave = threadIdx.x >> 6;
  int lane = threadIdx.x & 63;
  int half = lane >> 5;
  int l = lane & 31;
  int row = blockIdx.x * 8 + wave * 2 + half;
  float s1 = 0.f, s2 = 0.f;
  const unsigned short* hbs = (const unsigned short*)hb;

  if (row < N) {
    float di = dinv[row];
    int b0 = csr_ptr[row], b1 = csr_ptr[row + 1];
    ushort8v sv = *(const ushort8v*)(hbs + (size_t)row * 256 + l * 8);
    float acc[8];
#pragma unroll
    for (int c = 0; c < 8; ++c) acc[c] = bf2f(sv[c]) * di;

    for (int e = b0; e < b1; e += 8) {
      int idx[8];
#pragma unroll
      for (int j = 0; j < 8; ++j) {
        int ee = e + j;
        idx[j] = csr_src[ee < b1 ? ee : b1 - 1];
      }
      ushort8v v[8];
#pragma unroll
      for (int j = 0; j < 8; ++j)
        v[j] = *(const ushort8v*)(hbs + (size_t)idx[j] * 256 + l * 8);
      float w[8];
#pragma unroll
      for (int j = 0; j < 8; ++j) w[j] = dinv[idx[j]];
#pragma unroll
      for (int j = 0; j < 8; ++j) {
        float m = (e + j < b1) ? w[j] : 0.f;
#pragma unroll
        for (int c = 0; c < 8; ++c)
          acc[c] = fmaf(bf2f(v[j][c]), m, acc[c]);
      }
    }

    const f32x4 ba = *(const f32x4*)(conv_bias + l * 8);
    const f32x4 bb = *(const f32x4*)(conv_bias + l * 8 + 4);
    f32x4 o0, o1;
#pragma unroll
    for (int c = 0; c < 4; ++c) {
      o0[c] = fmaf(acc[c], di, ba[c]);
      o1[c] = fmaf(acc[c + 4], di, bb[c]);
    }
    float* orow = out + (size_t)row * 256 + l * 8;
    __builtin_nontemporal_store(o0, (f32x4*)orow);
    __builtin_nontemporal_store(o1, (f32x4*)(orow + 4));
#pragma unroll
    for (int c = 0; c < 4; ++c) {
      s1 += o0[c] + o1[c];
      s2 += o0[c] * o0[c] + o1[c] * o1[c];
    }
  }

  __shared__ float r1[256];
  __shared__ float r2[256];
  int t = threadIdx.x;
  r1[t] = s1;
  r2[t] = s2;
  __syncthreads();
  for (int off = 128; off > 0; off >>= 1) {
    if (t < off) { r1[t] += r1[t + off]; r2[t] += r2[t + off]; }
    __syncthreads();
  }
  if (t == 0) {
    double2 pp;
    pp.x = (double)r1[0];
    pp.y = (double)r2[0];
    partials[blockIdx.x] = pp;
  }
}

// ---- 7: redundant partials reduce + LayerNorm(graph) + PReLU ---------------

__global__ void norm_prelu(float* __restrict__ out, const double2* __restrict__ partials,
                           int nb, const float* __restrict__ lw, const float* __restrict__ lb,
                           const float* __restrict__ pa, int n4, double cnt) {
  __shared__ double q1[1024];
  __shared__ double q2[1024];
  __shared__ float sstats[2];
  int t = threadIdx.x;
  double a1 = 0.0, a2 = 0.0;
  for (int i = t; i < nb; i += 1024) {
    double2 pp = partials[i];
    a1 += pp.x;
    a2 += pp.y;
  }
  q1[t] = a1;
  q2[t] = a2;
  __syncthreads();
  for (int off = 512; off > 0; off >>= 1) {
    if (t < off) { q1[t] += q1[t + off]; q2[t] += q2[t + off]; }
    __syncthreads();
  }
  if (t == 0) {
    double mu = q1[0] / cnt;
    double var = q2[0] / cnt - mu * mu;
    if (var < 0) var = 0;
    sstats[0] = (float)mu;
    sstats[1] = (float)(1.0 / (sqrt(var) + (double)EPSV));
  }
  __syncthreads();
  float mu = sstats[0];
  float inv = sstats[1];
  float a = pa[0];
  int stride = gridDim.x * 1024;
  for (int i = blockIdx.x * 1024 + t; i < n4; i += stride) {
    int c4 = (i & 63) * 4;
    const f32x4 w = *(const f32x4*)(lw + c4);
    const f32x4 b = *(const f32x4*)(lb + c4);
    f32x4 v = __builtin_nontemporal_load((const f32x4*)(out + (size_t)i * 4));
    f32x4 y;
#pragma unroll
    for (int j = 0; j < 4; ++j) {
      float yv = (v[j] - mu) * inv * w[j] + b[j];
      y[j] = yv >= 0.f ? yv : a * yv;
    }
    __builtin_nontemporal_store(y, (f32x4*)(out + (size_t)i * 4));
  }
}

// ---- launch ---------------------------------------------------------------

extern "C" void kernel_launch(void* const* d_in, const int* in_sizes, int n_in,
                              void* d_out, int out_size, void* d_ws, size_t ws_size,
                              hipStream_t stream) {
  const float* x = (const float*)d_in[0];
  const int* eidx = (const int*)d_in[1];
  const float* W = (const float*)d_in[3];
  const float* conv_bias = (const float*)d_in[4];
  const float* ln_w = (const float*)d_in[5];
  const float* ln_b = (const float*)d_in[6];
  const float* prelu_a = (const float*)d_in[7];
  float* out = (float*)d_out;

  int N = in_sizes[0] / F;
  int E = in_sizes[1] / 2;
  const int* src = eidx;
  const int* dst = eidx + E;

  int nAggBlocks = (N + 7) / 8;
  int eb = (E + 255) / 256;
  int gemmb = (N + 63) / 64;
  int NB = (N + 255) / 256;  // 196 <= 256 (write_csr folded-scan requirement)

  char* p = (char*)d_ws;
  auto carve = [&](size_t bytes) { char* r = p; p += (bytes + 255) & ~(size_t)255; return r; };
  ushort4* hb    = (ushort4*)carve((size_t)N * 64 * sizeof(ushort4));  // bf16 h (unscaled)
  unsigned short* Wb = (unsigned short*)carve((size_t)F * F * sizeof(short));
  int* deg_cnt   = (int*)carve((size_t)N * sizeof(int));
  int* packed    = (int*)carve((size_t)E * sizeof(int));
  float* dinv    = (float*)carve((size_t)N * sizeof(float));
  int* csr_ptr   = (int*)carve((size_t)(N + 1) * sizeof(int));
  int* csr_src   = (int*)carve((size_t)E * sizeof(int));
  int* bsum      = (int*)carve((size_t)NB * sizeof(int));
  double2* partials = (double2*)carve((size_t)nAggBlocks * sizeof(double2));

  init_prep<<<NB + 256, 256, 0, stream>>>(deg_cnt, N, NB, W, Wb);
  count_gemm<<<eb + gemmb, 256, 0, stream>>>(dst, deg_cnt, packed, E, eb, x, Wb, hb, N);
  block_sums<<<NB, 256, 0, stream>>>(deg_cnt, bsum, dinv, N);
  write_csr<<<NB, 256, 0, stream>>>(deg_cnt, bsum, csr_ptr, N, E, NB);
  fill<<<eb, 256, 0, stream>>>(src, packed, csr_ptr, csr_src, E);
  aggregate<<<nAggBlocks, 256, 0, stream>>>(hb, csr_ptr, csr_src, dinv,
                                            conv_bias, out, partials, N);
  int n4 = N * (F / 4);
  norm_prelu<<<256, 1024, 0, stream>>>(out, partials, nAggBlocks, ln_w, ln_b, prelu_a,
                                       n4, (double)N * (double)F);
}

// Round 15
// 260.833 us; speedup vs baseline: 1.0877x; 1.0063x over previous
//
#include <hip/hip_runtime.h>
#include <hip/hip_bf16.h>

// GCNBlock: 7-dispatch pipeline (R14 = R12 + bf16 pre-LN staging, NO coop).
//   1 init_prep:  zero deg_cnt ; repack W -> Wb bf16
//   2 count_gemm: count edges -> packed(rank<<17|dst) || 64-row GEMM (62us)
//   3 block_sums: per-block degree sums + dinv
//   4 write_csr:  folded bsum scan + local scan (monotone CSR)
//   5 fill:       contention-free scatter via packed
//   6 aggregate:  R9 wide gather; stores pre-LN row as bf16 hagg (25.6MB,
//                 was 51.2MB f32) -- stats still computed on f32 accs
//   7 norm_prelu: reads hagg bf16 (25.6MB, was 51.2MB f32 re-read), writes
//                 final f32 out once.  Net -51.2MB HBM vs R12.
// R13 lesson: cooperative tail never executed (absmax == max|ref| -> out
// stayed zero; coop launch path failed silently). Same traffic win captured
// here with plain dispatches. R14 bench was an infra failure (container),
// not a kernel failure -- resubmitted unchanged.
// Ledger: R4 1-addr f64 atomics; R5 atomic-bump fill; R6 mega-fusion spill;
// R7 bucket-order locality; R8 dep-chain scatter; R10 2-phase gemm; R11
// quadratic csr fuse.
// N=50000, E=800000, F=256

#define F 256
#define EPSV 1e-5f

typedef __attribute__((ext_vector_type(8))) short short8;
typedef __attribute__((ext_vector_type(8))) unsigned short ushort8v;
typedef __attribute__((ext_vector_type(4))) float f32x4;

__device__ __forceinline__ unsigned short f2bf(float f) {
  union { float f; unsigned u; } v; v.f = f;
  unsigned r = v.u + 0x7fffu + ((v.u >> 16) & 1u);  // RNE
  return (unsigned short)(r >> 16);
}

__device__ __forceinline__ float bf2f(unsigned short u) {
  union { unsigned u; float f; } v; v.u = ((unsigned)u) << 16; return v.f;
}

// ---- 1: zero deg_cnt (blocks < NB) ; prep Wb (blocks >= NB) ----------------

__global__ void init_prep(int* __restrict__ deg_cnt, int N, int NB,
                          const float* __restrict__ W, unsigned short* __restrict__ Wb) {
  if ((int)blockIdx.x < NB) {
    int i = blockIdx.x * 256 + threadIdx.x;
    if (i < N) deg_cnt[i] = 0;
    return;
  }
  int gid = (blockIdx.x - NB) * 256 + threadIdx.x;  // 65536 total
  int j = gid & 7;
  int lane = (gid >> 3) & 63;
  int kc = (gid >> 9) & 7;
  int tt = gid >> 12;
  int k = kc * 32 + (lane >> 4) * 8 + j;
  int n = tt * 16 + (lane & 15);
  Wb[gid] = f2bf(W[k * 256 + n]);
}

// ---- 2: count+pack (blocks < eb) ; gemm 64-row tiles (blocks >= eb) --------
// packed[e] = (rank << 17) | dst.  GEMM writes h bf16 UNSCALED.

__global__ void count_gemm(const int* __restrict__ dst, int* __restrict__ deg_cnt,
                           int* __restrict__ packed, int E, int eb,
                           const float* __restrict__ x, const unsigned short* __restrict__ Wb,
                           ushort4* __restrict__ hb, int N) {
  // +8 pad: row stride 528B -> conflict-free ds_read_b128 fragments.
  __shared__ unsigned short A[64][264];  // 33792 B

  if ((int)blockIdx.x < eb) {
    int e = blockIdx.x * 256 + threadIdx.x;
    if (e < E) {
      int d = dst[e];
      int pos = atomicAdd(&deg_cnt[d], 1);
      packed[e] = (pos << 17) | d;
    }
    return;
  }

  int m0 = (blockIdx.x - eb) * 64;
  int t = threadIdx.x;
  int lane = t & 63;
  int wave = t >> 6;
  int q = lane >> 4;

  // stage A: 64 rows x 256 cols fp32->bf16, coalesced
#pragma unroll
  for (int j = 0; j < 16; ++j) {
    int idx = j * 256 + t;
    int row = idx >> 6;
    int c4 = idx & 63;
    int gr = m0 + row;
    int grc = gr < N ? gr : N - 1;
    f32x4 v = __builtin_nontemporal_load((const f32x4*)(x + (size_t)grc * F + c4 * 4));
    ushort4 u;
    u.x = f2bf(v[0]); u.y = f2bf(v[1]); u.z = f2bf(v[2]); u.w = f2bf(v[3]);
    *(ushort4*)&A[row][c4 * 4] = u;
  }
  __syncthreads();

  f32x4 acc[4][4];
#pragma unroll
  for (int m = 0; m < 4; ++m)
#pragma unroll
    for (int tt = 0; tt < 4; ++tt)
      acc[m][tt] = (f32x4){0.f, 0.f, 0.f, 0.f};

  int arow = lane & 15;
  for (int kc = 0; kc < 8; ++kc) {
    short8 a[4];
#pragma unroll
    for (int m = 0; m < 4; ++m)
      a[m] = *(const short8*)&A[m * 16 + arow][kc * 32 + q * 8];
#pragma unroll
    for (int tt = 0; tt < 4; ++tt) {
      const short8 b = *(const short8*)(Wb + (((wave * 4 + tt) * 8 + kc) * 64 + lane) * 8);
#pragma unroll
      for (int m = 0; m < 4; ++m)
        acc[m][tt] = __builtin_amdgcn_mfma_f32_16x16x32_bf16(a[m], b, acc[m][tt], 0, 0, 0);
    }
  }
  __syncthreads();

  // epilogue: bf16 repack via LDS, coalesced store (h UNSCALED)
  int ccol = lane & 15;
#pragma unroll
  for (int m = 0; m < 4; ++m) {
#pragma unroll
    for (int rr = 0; rr < 4; ++rr) {
      int lrow = m * 16 + q * 4 + rr;
#pragma unroll
      for (int tt = 0; tt < 4; ++tt)
        A[lrow][(wave * 4 + tt) * 16 + ccol] = f2bf(acc[m][tt][rr]);
    }
  }
  __syncthreads();
#pragma unroll
  for (int j = 0; j < 16; ++j) {
    int idx = j * 256 + t;
    int row = idx >> 6;
    int c4 = idx & 63;
    int grow = m0 + row;
    if (grow < N) hb[(size_t)grow * 64 + c4] = *(const ushort4*)&A[row][c4 * 4];
  }
}

// ---- 3: per-block degree sums + dinv ---------------------------------------

__global__ void block_sums(const int* __restrict__ deg_cnt, int* __restrict__ bsum,
                           float* __restrict__ dinv, int N) {
  __shared__ int s[256];
  int t = threadIdx.x;
  int i = blockIdx.x * 256 + t;
  int d = (i < N) ? deg_cnt[i] : 0;
  if (i < N) dinv[i] = rsqrtf((float)(d + 1));  // +1 self loop
  s[t] = d;
  __syncthreads();
  for (int off = 128; off > 0; off >>= 1) {
    if (t < off) s[t] += s[t + off];
    __syncthreads();
  }
  if (t == 0) bsum[blockIdx.x] = s[0];
}

// ---- 4: write_csr with folded bsum scan (NB <= 256) ------------------------

__global__ void write_csr(const int* __restrict__ deg_cnt, const int* __restrict__ bsum,
                          int* __restrict__ csr_ptr, int N, int E, int NB) {
  __shared__ int sb[256];
  __shared__ int s[256];
  int t = threadIdx.x;
  int bv = (t < NB) ? bsum[t] : 0;
  sb[t] = bv;
  __syncthreads();
  for (int off = 1; off < 256; off <<= 1) {
    int xx = (t >= off) ? sb[t - off] : 0;
    __syncthreads();
    sb[t] += xx;
    __syncthreads();
  }
  int boff = (blockIdx.x > 0) ? sb[blockIdx.x - 1] : 0;
  int i = blockIdx.x * 256 + t;
  int v = (i < N) ? deg_cnt[i] : 0;
  s[t] = v;
  __syncthreads();
  for (int off = 1; off < 256; off <<= 1) {
    int xx = (t >= off) ? s[t - off] : 0;
    __syncthreads();
    s[t] += xx;
    __syncthreads();
  }
  if (i < N) csr_ptr[i] = boff + s[t] - v;
  if (i == 0) csr_ptr[N] = E;
}

// ---- 5: fill via packed(rank,dst) (contention-free scatter) ----------------

__global__ void fill(const int* __restrict__ src, const int* __restrict__ packed,
                     const int* __restrict__ csr_ptr, int* __restrict__ csr_src, int E) {
  int e = blockIdx.x * 256 + threadIdx.x;
  if (e < E) {
    int pk = packed[e];
    int d = pk & 0x1FFFF;
    int r = pk >> 17;
    csr_src[csr_ptr[d] + r] = src[e];
  }
}

// ---- 6: aggregate -- 2 rows/wave, 32 lanes x 16B; pre-LN row -> bf16 hagg --
// hb UNSCALED; weight w[j] = dinv[src_j] (0 for pad).  Stats on f32 accs;
// stored values rounded once to bf16 (re-read by norm_prelu).

__global__ void aggregate(const ushort4* __restrict__ hb, const int* __restrict__ csr_ptr,
                          const int* __restrict__ csr_src, const float* __restrict__ dinv,
                          const float* __restrict__ conv_bias, ushort8v* __restrict__ hagg,
                          double2* __restrict__ partials, int N) {
  int wave = threadIdx.x >> 6;
  int lane = threadIdx.x & 63;
  int half = lane >> 5;
  int l = lane & 31;
  int row = blockIdx.x * 8 + wave * 2 + half;
  float s1 = 0.f, s2 = 0.f;
  const unsigned short* hbs = (const unsigned short*)hb;

  if (row < N) {
    float di = dinv[row];
    int b0 = csr_ptr[row], b1 = csr_ptr[row + 1];
    ushort8v sv = *(const ushort8v*)(hbs + (size_t)row * 256 + l * 8);
    float acc[8];
#pragma unroll
    for (int c = 0; c < 8; ++c) acc[c] = bf2f(sv[c]) * di;

    for (int e = b0; e < b1; e += 8) {
      int idx[8];
#pragma unroll
      for (int j = 0; j < 8; ++j) {
        int ee = e + j;
        idx[j] = csr_src[ee < b1 ? ee : b1 - 1];
      }
      ushort8v v[8];
#pragma unroll
      for (int j = 0; j < 8; ++j)
        v[j] = *(const ushort8v*)(hbs + (size_t)idx[j] * 256 + l * 8);
      float w[8];
#pragma unroll
      for (int j = 0; j < 8; ++j) w[j] = dinv[idx[j]];
#pragma unroll
      for (int j = 0; j < 8; ++j) {
        float m = (e + j < b1) ? w[j] : 0.f;
#pragma unroll
        for (int c = 0; c < 8; ++c)
          acc[c] = fmaf(bf2f(v[j][c]), m, acc[c]);
      }
    }

    const f32x4 ba = *(const f32x4*)(conv_bias + l * 8);
    const f32x4 bb = *(const f32x4*)(conv_bias + l * 8 + 4);
    ushort8v kp;
#pragma unroll
    for (int c = 0; c < 4; ++c) {
      acc[c] = fmaf(acc[c], di, ba[c]);
      acc[c + 4] = fmaf(acc[c + 4], di, bb[c]);
    }
#pragma unroll
    for (int c = 0; c < 8; ++c) {
      s1 += acc[c];
      s2 += acc[c] * acc[c];
      kp[c] = f2bf(acc[c]);
    }
    __builtin_nontemporal_store(kp, &hagg[(size_t)row * 32 + l]);
  }

  __shared__ float r1[256];
  __shared__ float r2[256];
  int t = threadIdx.x;
  r1[t] = s1;
  r2[t] = s2;
  __syncthreads();
  for (int off = 128; off > 0; off >>= 1) {
    if (t < off) { r1[t] += r1[t + off]; r2[t] += r2[t + off]; }
    __syncthreads();
  }
  if (t == 0) {
    double2 pp;
    pp.x = (double)r1[0];
    pp.y = (double)r2[0];
    partials[blockIdx.x] = pp;
  }
}

// ---- 7: partials reduce + LayerNorm(graph) + PReLU; hagg bf16 -> out f32 ---

__global__ void norm_prelu(const ushort8v* __restrict__ hagg, float* __restrict__ out,
                           const double2* __restrict__ partials, int nb,
                           const float* __restrict__ lw, const float* __restrict__ lb,
                           const float* __restrict__ pa, int n8, double cnt) {
  __shared__ double q1[1024];
  __shared__ double q2[1024];
  __shared__ float sstats[2];
  int t = threadIdx.x;
  double a1 = 0.0, a2 = 0.0;
  for (int i = t; i < nb; i += 1024) {
    double2 pp = partials[i];
    a1 += pp.x;
    a2 += pp.y;
  }
  q1[t] = a1;
  q2[t] = a2;
  __syncthreads();
  for (int off = 512; off > 0; off >>= 1) {
    if (t < off) { q1[t] += q1[t + off]; q2[t] += q2[t + off]; }
    __syncthreads();
  }
  if (t == 0) {
    double mu = q1[0] / cnt;
    double var = q2[0] / cnt - mu * mu;
    if (var < 0) var = 0;
    sstats[0] = (float)mu;
    sstats[1] = (float)(1.0 / (sqrt(var) + (double)EPSV));
  }
  __syncthreads();
  float mu = sstats[0];
  float inv = sstats[1];
  float a = pa[0];
  int stride = gridDim.x * 1024;
  for (int i = blockIdx.x * 1024 + t; i < n8; i += stride) {
    int c8 = (i & 31) * 8;
    const f32x4 w0 = *(const f32x4*)(lw + c8);
    const f32x4 w1 = *(const f32x4*)(lw + c8 + 4);
    const f32x4 b0 = *(const f32x4*)(lb + c8);
    const f32x4 b1 = *(const f32x4*)(lb + c8 + 4);
    ushort8v kp = __builtin_nontemporal_load(&hagg[i]);
    f32x4 o0, o1;
#pragma unroll
    for (int c = 0; c < 4; ++c) {
      float y0 = (bf2f(kp[c]) - mu) * inv * w0[c] + b0[c];
      float y1 = (bf2f(kp[c + 4]) - mu) * inv * w1[c] + b1[c];
      o0[c] = y0 >= 0.f ? y0 : a * y0;
      o1[c] = y1 >= 0.f ? y1 : a * y1;
    }
    float* orow = out + (size_t)i * 8;
    __builtin_nontemporal_store(o0, (f32x4*)orow);
    __builtin_nontemporal_store(o1, (f32x4*)(orow + 4));
  }
}

// ---- launch ---------------------------------------------------------------

extern "C" void kernel_launch(void* const* d_in, const int* in_sizes, int n_in,
                              void* d_out, int out_size, void* d_ws, size_t ws_size,
                              hipStream_t stream) {
  const float* x = (const float*)d_in[0];
  const int* eidx = (const int*)d_in[1];
  const float* W = (const float*)d_in[3];
  const float* conv_bias = (const float*)d_in[4];
  const float* ln_w = (const float*)d_in[5];
  const float* ln_b = (const float*)d_in[6];
  const float* prelu_a = (const float*)d_in[7];
  float* out = (float*)d_out;

  int N = in_sizes[0] / F;
  int E = in_sizes[1] / 2;
  const int* src = eidx;
  const int* dst = eidx + E;

  int nAggBlocks = (N + 7) / 8;
  int eb = (E + 255) / 256;
  int gemmb = (N + 63) / 64;
  int NB = (N + 255) / 256;  // 196 <= 256 (write_csr folded-scan requirement)

  char* p = (char*)d_ws;
  auto carve = [&](size_t bytes) { char* r = p; p += (bytes + 255) & ~(size_t)255; return r; };
  ushort4* hb    = (ushort4*)carve((size_t)N * 64 * sizeof(ushort4));   // bf16 h (unscaled)
  ushort8v* hagg = (ushort8v*)carve((size_t)N * 32 * sizeof(ushort8v)); // bf16 pre-LN rows
  unsigned short* Wb = (unsigned short*)carve((size_t)F * F * sizeof(short));
  int* deg_cnt   = (int*)carve((size_t)N * sizeof(int));
  int* packed    = (int*)carve((size_t)E * sizeof(int));
  float* dinv    = (float*)carve((size_t)N * sizeof(float));
  int* csr_ptr   = (int*)carve((size_t)(N + 1) * sizeof(int));
  int* csr_src   = (int*)carve((size_t)E * sizeof(int));
  int* bsum      = (int*)carve((size_t)NB * sizeof(int));
  double2* partials = (double2*)carve((size_t)nAggBlocks * sizeof(double2));

  init_prep<<<NB + 256, 256, 0, stream>>>(deg_cnt, N, NB, W, Wb);
  count_gemm<<<eb + gemmb, 256, 0, stream>>>(dst, deg_cnt, packed, E, eb, x, Wb, hb, N);
  block_sums<<<NB, 256, 0, stream>>>(deg_cnt, bsum, dinv, N);
  write_csr<<<NB, 256, 0, stream>>>(deg_cnt, bsum, csr_ptr, N, E, NB);
  fill<<<eb, 256, 0, stream>>>(src, packed, csr_ptr, csr_src, E);
  aggregate<<<nAggBlocks, 256, 0, stream>>>(hb, csr_ptr, csr_src, dinv,
                                            conv_bias, hagg, partials, N);
  int n8 = N * 32;  // ushort8 groups (8 features each)
  norm_prelu<<<256, 1024, 0, stream>>>(hagg, out, partials, nAggBlocks,
                                       ln_w, ln_b, prelu_a, n8, (double)N * (double)F);
}